// Round 15
// baseline (460.202 us; speedup 1.0000x reference)
//
#include <hip/hip_runtime.h>

#define NN 32768   // nodes
#define NE 524288  // edges

typedef __attribute__((ext_vector_type(8))) short bf16x8;
typedef __attribute__((ext_vector_type(4))) float f32x4;

__device__ __forceinline__ unsigned short f2bf(float f) {
  unsigned int u = __float_as_uint(f);
  unsigned int r = (u + 0x7FFFu + ((u >> 16) & 1u)) >> 16;
  return (unsigned short)r;
}
__device__ __forceinline__ float bf2f(unsigned short s) {
  return __uint_as_float(((unsigned int)s) << 16);
}

// wave-level LDS fence: HW-drain this wave's DS ops + stop compiler reordering
__device__ __forceinline__ void lds_fence_wave() {
  asm volatile("s_waitcnt lgkmcnt(0)" ::: "memory");
  __builtin_amdgcn_sched_barrier(0);
}

// ---------------- generic fragment pack (device body) ----------------
// B-operand fragment order: frag fi = kc*(N/16)+nt, elem j:
// v[j] = W[l][row0 + kc*32 + 8*(lane>>4) + j][nt*16 + (lane&15)]
__device__ __forceinline__ void prep_frag_body(
    const float* __restrict__ W, int row0, int ldw, long lstrW,
    unsigned short* __restrict__ out, int outOff, int outLstr,
    int K, int N, int t, int total) {
  if (t >= total) return;
  int lane = t & 63, fi = t >> 6;
  int FR = (K >> 5) * (N >> 4);
  int l = fi / FR; fi -= l * FR;
  int NT = N >> 4;
  int nt = fi % NT, kc = fi / NT;
  int i = lane & 15, g = lane >> 4;
  const float* base = W + (long)l * lstrW;
  bf16x8 v;
#pragma unroll
  for (int j = 0; j < 8; ++j)
    v[j] = (short)f2bf(base[(long)(row0 + kc * 32 + g * 8 + j) * ldw + nt * 16 + i]);
  reinterpret_cast<bf16x8*>(out)[(long)(l * outLstr + outOff + fi) * 64 + lane] = v;
}

// all weight fragment packs in one dispatch (block-range switch)
__global__ void prep_all_kernel(const float* __restrict__ emb_w,
                                const float* __restrict__ msg_w1,
                                const float* __restrict__ upd_w,
                                const float* __restrict__ wcomp,
                                const float* __restrict__ proj_w,
                                unsigned short* __restrict__ wembf,
                                unsigned short* __restrict__ w1af,
                                unsigned short* __restrict__ w1bf,
                                unsigned short* __restrict__ w1cf,
                                unsigned short* __restrict__ wupdf,
                                unsigned short* __restrict__ wprojf) {
  int b = blockIdx.x, tid = threadIdx.x;
  if (b < 4)        prep_frag_body(emb_w,  0,   128, 0,     wembf,  0,  16, 64,  128, b * 256 + tid, 1024);
  else if (b < 52)  prep_frag_body(msg_w1, 0,   256, 73728, w1af,   0,  64, 128, 256, (b - 4) * 256 + tid, 12288);
  else if (b < 100) prep_frag_body(msg_w1, 128, 256, 73728, w1bf,   0,  64, 128, 256, (b - 52) * 256 + tid, 12288);
  else if (b < 112) prep_frag_body(msg_w1, 256, 256, 73728, w1cf,   0,  16, 32,  256, (b - 100) * 256 + tid, 3072);
  else if (b < 136) prep_frag_body(upd_w,  0,   128, 32768, wupdf,  0,  96, 128, 128, (b - 112) * 256 + tid, 6144);
  else if (b < 184) prep_frag_body(wcomp,  0,   128, 32768, wupdf,  32, 96, 256, 128, (b - 136) * 256 + tid, 12288);
  else              prep_frag_body(proj_w, 0,   256, 0,     wprojf, 0,  64, 128, 256, (b - 184) * 256 + tid, 4096);
}

// ---------------- Wcomp = W2 @ Wu_bot  (+ c2 = b2 @ Wu_bot tail) ----------
__global__ void wcomp_kernel(const float* __restrict__ W2, const float* __restrict__ Wu,
                             const float* __restrict__ b2,
                             float* __restrict__ out, float* __restrict__ c2out) {
  int t = blockIdx.x * 256 + threadIdx.x;
  if (t < 3 * 256 * 128) {
    int c = t & 127, a = (t >> 7) & 255, l = t >> 15;
    const float* w2 = W2 + (long)l * 32768 + a * 128;
    const float* wu = Wu + (long)l * 32768 + 128 * 128 + c;
    float s = 0.f;
#pragma unroll 8
    for (int j = 0; j < 128; ++j) s += w2[j] * wu[j * 128];
    out[t] = s;
  } else {
    int t2 = t - 3 * 256 * 128;
    if (t2 < 3 * 128) {
      int c = t2 & 127, l = t2 >> 7;
      const float* bb = b2 + l * 128;
      const float* wu = Wu + (long)l * 32768 + 128 * 128 + c;
      float s = 0.f;
#pragma unroll 8
      for (int j = 0; j < 128; ++j) s += bb[j] * wu[j * 128];
      c2out[t2] = s;
    }
  }
}

// ---------------- sort edges by dst ----------------
__global__ void hist_kernel(const int* __restrict__ eidx, int* __restrict__ deg) {
  int t = blockIdx.x * 256 + threadIdx.x;
  if (t < NE) atomicAdd(&deg[eidx[NE + t]], 1);
}

__global__ void scan_kernel(const int* __restrict__ deg, int* __restrict__ cursor,
                            float* __restrict__ degf) {
  __shared__ int lds[1024];
  int t = threadIdx.x;
  int vals[32];
  int s = 0;
#pragma unroll
  for (int j = 0; j < 32; ++j) {
    int d = deg[t * 32 + j];
    vals[j] = d; s += d;
    degf[t * 32 + j] = (float)d;
  }
  lds[t] = s;
  __syncthreads();
  for (int off = 1; off < 1024; off <<= 1) {
    int tmp = 0;
    if (t >= off) tmp = lds[t - off];
    __syncthreads();
    lds[t] += tmp;
    __syncthreads();
  }
  int run = lds[t] - s;  // exclusive prefix
#pragma unroll
  for (int j = 0; j < 32; ++j) { cursor[t * 32 + j] = run; run += vals[j]; }
}

// dsts is determined by the histogram: dsts[start_n .. start_n+deg_n) = n.
// Generate it coalesced instead of scatter's 16x-amplified random 4B writes.
__global__ void fill_dsts_kernel(const int* __restrict__ deg, const int* __restrict__ cursor,
                                 int* __restrict__ dsts) {
  int n = blockIdx.x * 256 + threadIdx.x;
  if (n >= NN) return;
  int st = cursor[n], de = deg[n];
  for (int j = 0; j < de; ++j) dsts[st + j] = n;
}

// scatter edges into dst-sorted order (srcs + permuted/cvt edge_attr only)
__global__ void scatter_kernel(const int* __restrict__ eidx, const float* __restrict__ ea,
                               int* __restrict__ cursor,
                               int* __restrict__ srcs,
                               unsigned short* __restrict__ ea_s) {
  int t = blockIdx.x * 256 + threadIdx.x;
  if (t >= NE) return;
  int d = eidx[NE + t], s = eidx[t];
  int pos = atomicAdd(&cursor[d], 1);
  srcs[pos] = s;
  const float4* ep = reinterpret_cast<const float4*>(ea + (long)t * 32);
  unsigned short* op = ea_s + (long)pos * 32;
#pragma unroll
  for (int q = 0; q < 4; ++q) {
    float4 f0 = ep[2 * q], f1 = ep[2 * q + 1];
    bf16x8 v;
    v[0] = (short)f2bf(f0.x); v[1] = (short)f2bf(f0.y);
    v[2] = (short)f2bf(f0.z); v[3] = (short)f2bf(f0.w);
    v[4] = (short)f2bf(f1.x); v[5] = (short)f2bf(f1.y);
    v[6] = (short)f2bf(f1.z); v[7] = (short)f2bf(f1.w);
    *reinterpret_cast<bf16x8*>(op + q * 8) = v;
  }
}

// ---------------- node embedding: h = x @ We + be (bf16 spine only) --------
__global__ __launch_bounds__(256, 2)
void node_emb_kernel(const float* __restrict__ x,
                     const unsigned short* __restrict__ wf,
                     const float* __restrict__ bias,
                     unsigned short* __restrict__ h_bf) {
  int tid = threadIdx.x, lane = tid & 63, w = tid >> 6;
  int i = lane & 15, g = lane >> 4;
  int nbase = blockIdx.x * 64 + w * 16;
  f32x4 zero = {0.f, 0.f, 0.f, 0.f};
  f32x4 acc[8];
#pragma unroll
  for (int nt = 0; nt < 8; ++nt) acc[nt] = zero;
#pragma unroll
  for (int kc = 0; kc < 2; ++kc) {
    const float* xp = x + (nbase + i) * 64 + kc * 32 + g * 8;
    float4 f0 = *reinterpret_cast<const float4*>(xp);
    float4 f1 = *reinterpret_cast<const float4*>(xp + 4);
    bf16x8 af;
    af[0] = (short)f2bf(f0.x); af[1] = (short)f2bf(f0.y);
    af[2] = (short)f2bf(f0.z); af[3] = (short)f2bf(f0.w);
    af[4] = (short)f2bf(f1.x); af[5] = (short)f2bf(f1.y);
    af[6] = (short)f2bf(f1.z); af[7] = (short)f2bf(f1.w);
#pragma unroll
    for (int nt = 0; nt < 8; ++nt) {
      bf16x8 bf = reinterpret_cast<const bf16x8*>(wf)[(kc * 8 + nt) * 64 + lane];
      acc[nt] = __builtin_amdgcn_mfma_f32_16x16x32_bf16(af, bf, acc[nt], 0, 0, 0);
    }
  }
#pragma unroll
  for (int nt = 0; nt < 8; ++nt) {
    int c = nt * 16 + i;
    float b = bias[c];
#pragma unroll
    for (int r = 0; r < 4; ++r) {
      int node = nbase + 4 * g + r;
      h_bf[node * 128 + c] = f2bf(acc[nt][r] + b);
    }
  }
}

// ---------------- P = h@W1a + b1, Q = h@W1b; zero haggr; coalesced stores --
__global__ __launch_bounds__(256, 2)
void pq_kernel(const unsigned short* __restrict__ h_bf,
               const unsigned short* __restrict__ wfa,
               const unsigned short* __restrict__ wfb,
               const float* __restrict__ b1,
               unsigned short* __restrict__ P, unsigned short* __restrict__ Q,
               float* __restrict__ haggr) {
  __shared__ unsigned short xpose[64 * 264];  // 33792 B repack buffer
  int tid = threadIdx.x, lane = tid & 63, w = tid >> 6;
  int i = lane & 15, g = lane >> 4;
  int nbase = blockIdx.x * 64 + w * 16;
  // zero this block's 64 haggr rows (replaces hipMemsetAsync)
  {
    const float4 zz = make_float4(0.f, 0.f, 0.f, 0.f);
    float4* hz = reinterpret_cast<float4*>(haggr + (long)blockIdx.x * 64 * 256);
#pragma unroll
    for (int it = 0; it < 16; ++it) hz[tid + 256 * it] = zz;
  }
  f32x4 zero = {0.f, 0.f, 0.f, 0.f};
  f32x4 accP[16], accQ[16];
#pragma unroll
  for (int nt = 0; nt < 16; ++nt) { accP[nt] = zero; accQ[nt] = zero; }
#pragma unroll
  for (int kc = 0; kc < 4; ++kc) {
    bf16x8 af = *reinterpret_cast<const bf16x8*>(h_bf + (nbase + i) * 128 + kc * 32 + g * 8);
#pragma unroll
    for (int nt = 0; nt < 16; ++nt) {
      bf16x8 ba = reinterpret_cast<const bf16x8*>(wfa)[(kc * 16 + nt) * 64 + lane];
      accP[nt] = __builtin_amdgcn_mfma_f32_16x16x32_bf16(af, ba, accP[nt], 0, 0, 0);
      bf16x8 bb = reinterpret_cast<const bf16x8*>(wfb)[(kc * 16 + nt) * 64 + lane];
      accQ[nt] = __builtin_amdgcn_mfma_f32_16x16x32_bf16(af, bb, accQ[nt], 0, 0, 0);
    }
  }
  const int rowBase = blockIdx.x * 64;
  // P: transpose through LDS -> coalesced bf16x8 stores
#pragma unroll
  for (int nt = 0; nt < 16; ++nt) {
    int c = nt * 16 + i;
    float b = b1[c];
#pragma unroll
    for (int r = 0; r < 4; ++r)
      xpose[(w * 16 + 4 * g + r) * 264 + c] = f2bf(accP[nt][r] + b);
  }
  __syncthreads();
#pragma unroll
  for (int it = 0; it < 8; ++it) {
    int idx = tid + 256 * it;
    int row = idx >> 5, ch8 = (idx & 31) * 8;
    bf16x8 v = *reinterpret_cast<const bf16x8*>(&xpose[row * 264 + ch8]);
    *reinterpret_cast<bf16x8*>(&P[(long)(rowBase + row) * 256 + ch8]) = v;
  }
  __syncthreads();
  // Q: same, reusing the buffer
#pragma unroll
  for (int nt = 0; nt < 16; ++nt) {
    int c = nt * 16 + i;
#pragma unroll
    for (int r = 0; r < 4; ++r)
      xpose[(w * 16 + 4 * g + r) * 264 + c] = f2bf(accQ[nt][r]);
  }
  __syncthreads();
#pragma unroll
  for (int it = 0; it < 8; ++it) {
    int idx = tid + 256 * it;
    int row = idx >> 5, ch8 = (idx & 31) * 8;
    bf16x8 v = *reinterpret_cast<const bf16x8*>(&xpose[row * 264 + ch8]);
    *reinterpret_cast<bf16x8*>(&Q[(long)(rowBase + row) * 256 + ch8]) = v;
  }
}

// ---------------- edge kernel v11: 1 wave x 32 edges ----------------------
// hidden = relu(P[dst] + Q[src] + R), dst-segmented sum -> haggr (fp32).
// One wave owns 32 dst-sorted edges: halves per-edge prologue cost and cuts
// flush rounds per edge ~25% (expected segments in 32 edges ~3 vs 2x2).
#define RP 264
__global__ __launch_bounds__(64, 2)
void edge_kernel11(const unsigned short* __restrict__ P,
                   const unsigned short* __restrict__ Q,
                   const int* __restrict__ dsts, const int* __restrict__ srcs,
                   const unsigned short* __restrict__ ea_s,
                   const unsigned short* __restrict__ w1cf,
                   float* __restrict__ haggr) {
  __shared__ unsigned short R[32 * RP];   // 16896 B
  __shared__ float xch[256];              // flush transpose (1 KB)
  const int lane = threadIdx.x & 63;
  const int i = lane & 15, g = lane >> 4;
  // XCD-chunked bijective swizzle: nwg = 16384 = 8 * 2048
  const int bid = blockIdx.x;
  const int swz = (bid & 7) * 2048 + (bid >> 3);
  const int p0 = swz * 32;

  // indices: one vector load each (lanes 0-31 -> edges 0-31), then readlane
  int d32 = dsts[p0 + (lane & 31)];
  int s32 = srcs[p0 + (lane & 31)];

  const int c4 = lane * 4;
  // Q prefetch: consume src lanes immediately (keeps SGPR liveness low)
  ushort4 qv[32];
#pragma unroll
  for (int k = 0; k < 32; ++k) {
    int sv = __builtin_amdgcn_readlane(s32, k);
    qv[k] = *reinterpret_cast<const ushort4*>(Q + (long)sv * 256 + c4);
  }
  int dvs[32];
#pragma unroll
  for (int k = 0; k < 32; ++k) dvs[k] = __builtin_amdgcn_readlane(d32, k);
  ushort4 pv0 = *reinterpret_cast<const ushort4*>(P + (long)dvs[0] * 256 + c4);

  // R^T = W1c^T @ ea^T in two 16-edge halves: lane holds channels
  // m*16+4g..+3 of edge (half*16+i) -> b64 stores into R rows
#pragma unroll
  for (int half = 0; half < 2; ++half) {
    bf16x8 bfrag = *reinterpret_cast<const bf16x8*>(ea_s + (long)(p0 + half * 16 + i) * 32 + g * 8);
    f32x4 zero = {0.f, 0.f, 0.f, 0.f};
    f32x4 acc[16];
#pragma unroll
    for (int m = 0; m < 16; ++m) acc[m] = zero;
#pragma unroll
    for (int m = 0; m < 16; ++m) {
      bf16x8 afrag = reinterpret_cast<const bf16x8*>(w1cf)[m * 64 + lane];
      acc[m] = __builtin_amdgcn_mfma_f32_16x16x32_bf16(afrag, bfrag, acc[m], 0, 0, 0);
    }
#pragma unroll
    for (int m = 0; m < 16; ++m) {
      union { unsigned short s[4]; unsigned long long u; } pk;
#pragma unroll
      for (int r = 0; r < 4; ++r) pk.s[r] = f2bf(acc[m][r]);
      *reinterpret_cast<unsigned long long*>(&R[(half * 16 + i) * RP + m * 16 + 4 * g]) = pk.u;
    }
  }

  float pf[4];
  pf[0] = bf2f(pv0.x); pf[1] = bf2f(pv0.y); pf[2] = bf2f(pv0.z); pf[3] = bf2f(pv0.w);
  int dvPrev = dvs[0];

  lds_fence_wave();  // R wave-local producer->consumer ordering

  float acc4[4] = {0.f, 0.f, 0.f, 0.f};
#pragma unroll
  for (int k = 0; k < 32; ++k) {
    int dv = dvs[k];
    if (dv != dvPrev) {  // scalar branch (dvs in SGPRs)
      *reinterpret_cast<float4*>(&xch[c4]) = make_float4(acc4[0], acc4[1], acc4[2], acc4[3]);
      lds_fence_wave();
      float* hp = haggr + (long)dvPrev * 256;
#pragma unroll
      for (int j = 0; j < 4; ++j) atomicAdd(hp + lane + 64 * j, xch[lane + 64 * j]);
      acc4[0] = acc4[1] = acc4[2] = acc4[3] = 0.f;
      ushort4 pv = *reinterpret_cast<const ushort4*>(P + (long)dv * 256 + c4);
      pf[0] = bf2f(pv.x); pf[1] = bf2f(pv.y); pf[2] = bf2f(pv.z); pf[3] = bf2f(pv.w);
      dvPrev = dv;
    }
    ushort4 rv = *reinterpret_cast<const ushort4*>(&R[k * RP + c4]);
    float v0 = pf[0] + bf2f(qv[k].x) + bf2f(rv.x);
    float v1 = pf[1] + bf2f(qv[k].y) + bf2f(rv.y);
    float v2 = pf[2] + bf2f(qv[k].z) + bf2f(rv.z);
    float v3 = pf[3] + bf2f(qv[k].w) + bf2f(rv.w);
    acc4[0] += v0 > 0.f ? v0 : 0.f;
    acc4[1] += v1 > 0.f ? v1 : 0.f;
    acc4[2] += v2 > 0.f ? v2 : 0.f;
    acc4[3] += v3 > 0.f ? v3 : 0.f;
  }
  {
    *reinterpret_cast<float4*>(&xch[c4]) = make_float4(acc4[0], acc4[1], acc4[2], acc4[3]);
    lds_fence_wave();
    float* hp = haggr + (long)dvPrev * 256;
#pragma unroll
    for (int j = 0; j < 4; ++j) atomicAdd(hp + lane + 64 * j, xch[lane + 64 * j]);
  }
}

// ---------------- update: u=[h|haggr]@W+ub+deg*c2, relu,LN,+h,LN ----------
// residual taken from h_bf (bf16 spine; no fp32 h shadow)
__global__ __launch_bounds__(256, 2)
void upd_kernel2(const unsigned short* __restrict__ h_bf_in,
                 const float* __restrict__ haggr,
                 const float* __restrict__ degf,
                 const unsigned short* __restrict__ wf,
                 const float* __restrict__ ub, const float* __restrict__ c2,
                 const float* __restrict__ g1, const float* __restrict__ be1,
                 const float* __restrict__ g2, const float* __restrict__ be2,
                 unsigned short* __restrict__ h_bf_out) {
  int tid = threadIdx.x, lane = tid & 63, w = tid >> 6;
  int i = lane & 15, g = lane >> 4;
  int nbase = blockIdx.x * 64 + w * 16;
  f32x4 zero = {0.f, 0.f, 0.f, 0.f};
  f32x4 acc[8];
#pragma unroll
  for (int nt = 0; nt < 8; ++nt) acc[nt] = zero;
#pragma unroll
  for (int kc = 0; kc < 12; ++kc) {
    bf16x8 af;
    if (kc < 4) {
      af = *reinterpret_cast<const bf16x8*>(h_bf_in + (nbase + i) * 128 + kc * 32 + g * 8);
    } else {
      const float* ap = haggr + (long)(nbase + i) * 256 + (kc - 4) * 32 + g * 8;
      float4 f0 = *reinterpret_cast<const float4*>(ap);
      float4 f1 = *reinterpret_cast<const float4*>(ap + 4);
      af[0] = (short)f2bf(f0.x); af[1] = (short)f2bf(f0.y);
      af[2] = (short)f2bf(f0.z); af[3] = (short)f2bf(f0.w);
      af[4] = (short)f2bf(f1.x); af[5] = (short)f2bf(f1.y);
      af[6] = (short)f2bf(f1.z); af[7] = (short)f2bf(f1.w);
    }
#pragma unroll
    for (int nt = 0; nt < 8; ++nt) {
      bf16x8 bf = reinterpret_cast<const bf16x8*>(wf)[(kc * 8 + nt) * 64 + lane];
      acc[nt] = __builtin_amdgcn_mfma_f32_16x16x32_bf16(af, bf, acc[nt], 0, 0, 0);
    }
  }
  float vv[8][4];
#pragma unroll
  for (int nt = 0; nt < 8; ++nt) {
    int c = nt * 16 + i;
    float b = ub[c], cc = c2[c];
#pragma unroll
    for (int r = 0; r < 4; ++r) {
      int node = nbase + 4 * g + r;
      float t = acc[nt][r] + b + degf[node] * cc;
      vv[nt][r] = t > 0.f ? t : 0.f;
    }
  }
#pragma unroll
  for (int r = 0; r < 4; ++r) {
    float s = 0.f, s2 = 0.f;
#pragma unroll
    for (int nt = 0; nt < 8; ++nt) { s += vv[nt][r]; s2 += vv[nt][r] * vv[nt][r]; }
#pragma unroll
    for (int mk = 1; mk < 16; mk <<= 1) { s += __shfl_xor(s, mk, 64); s2 += __shfl_xor(s2, mk, 64); }
    float mean = s * (1.f / 128.f);
    float var = s2 * (1.f / 128.f) - mean * mean;
    float inv = rsqrtf(var + 1e-5f);
    int node = nbase + 4 * g + r;
    float tv[8];
    float sb = 0.f, sb2 = 0.f;
#pragma unroll
    for (int nt = 0; nt < 8; ++nt) {
      int c = nt * 16 + i;
      float u = (vv[nt][r] - mean) * inv * g1[c] + be1[c];
      float t = bf2f(h_bf_in[node * 128 + c]) + u;  // bf16 residual spine
      tv[nt] = t;
      sb += t; sb2 += t * t;
    }
#pragma unroll
    for (int mk = 1; mk < 16; mk <<= 1) { sb += __shfl_xor(sb, mk, 64); sb2 += __shfl_xor(sb2, mk, 64); }
    float mean2 = sb * (1.f / 128.f);
    float var2 = sb2 * (1.f / 128.f) - mean2 * mean2;
    float inv2 = rsqrtf(var2 + 1e-5f);
#pragma unroll
    for (int nt = 0; nt < 8; ++nt) {
      int c = nt * 16 + i;
      float o = (tv[nt] - mean2) * inv2 * g2[c] + be2[c];
      h_bf_out[node * 128 + c] = f2bf(o);
    }
  }
}

// ---------------- projection (+ mask fill) ----------------
__global__ __launch_bounds__(256, 2)
void proj_kernel(const unsigned short* __restrict__ h_bf,
                 const unsigned short* __restrict__ wf,
                 const float* __restrict__ bias,
                 float* __restrict__ out, float* __restrict__ mask) {
  int tid = threadIdx.x, lane = tid & 63, w = tid >> 6;
  int i = lane & 15, g = lane >> 4;
  int nbase = blockIdx.x * 64 + w * 16;
  if (tid < 64) mask[blockIdx.x * 64 + tid] = 1.0f;
  f32x4 zero = {0.f, 0.f, 0.f, 0.f};
  f32x4 acc[16];
#pragma unroll
  for (int nt = 0; nt < 16; ++nt) acc[nt] = zero;
#pragma unroll
  for (int kc = 0; kc < 4; ++kc) {
    bf16x8 af = *reinterpret_cast<const bf16x8*>(h_bf + (nbase + i) * 128 + kc * 32 + g * 8);
#pragma unroll
    for (int nt = 0; nt < 16; ++nt) {
      bf16x8 bf = reinterpret_cast<const bf16x8*>(wf)[(kc * 16 + nt) * 64 + lane];
      acc[nt] = __builtin_amdgcn_mfma_f32_16x16x32_bf16(af, bf, acc[nt], 0, 0, 0);
    }
  }
#pragma unroll
  for (int nt = 0; nt < 16; ++nt) {
    int c = nt * 16 + i;
    float b = bias[c];
#pragma unroll
    for (int r = 0; r < 4; ++r) {
      int node = nbase + 4 * g + r;
      out[(long)node * 256 + c] = acc[nt][r] + b;
    }
  }
}

// ---------------- launch ----------------
extern "C" void kernel_launch(void* const* d_in, const int* in_sizes, int n_in,
                              void* d_out, int out_size, void* d_ws, size_t ws_size,
                              hipStream_t stream) {
  const float* x      = (const float*)d_in[0];
  const float* ea     = (const float*)d_in[1];
  const float* emb_w  = (const float*)d_in[2];
  const float* emb_b  = (const float*)d_in[3];
  const float* msg_w1 = (const float*)d_in[4];
  const float* msg_b1 = (const float*)d_in[5];
  const float* msg_w2 = (const float*)d_in[6];
  const float* msg_b2 = (const float*)d_in[7];
  const float* upd_w  = (const float*)d_in[8];
  const float* upd_b  = (const float*)d_in[9];
  const float* uln_g  = (const float*)d_in[10];
  const float* uln_b  = (const float*)d_in[11];
  const float* nrm_g  = (const float*)d_in[12];
  const float* nrm_b  = (const float*)d_in[13];
  const float* proj_w = (const float*)d_in[14];
  const float* proj_b = (const float*)d_in[15];
  const int*   eidx   = (const int*)d_in[16];

  char* ws = (char*)d_ws;
  size_t off = 0;
  auto take = [&](size_t b) { char* p = ws + off; off = (off + b + 255) & ~(size_t)255; return p; };
  unsigned short* h_bf  = (unsigned short*)take((size_t)NN * 128 * 2);
  unsigned short* Pb    = (unsigned short*)take((size_t)NN * 256 * 2);
  unsigned short* Qb    = (unsigned short*)take((size_t)NN * 256 * 2);
  float*          haggr = (float*)take((size_t)NN * 256 * 4);
  unsigned short* ea_s  = (unsigned short*)take((size_t)NE * 32 * 2);
  int*            dsts  = (int*)take((size_t)NE * 4);
  int*            srcs  = (int*)take((size_t)NE * 4);
  int*            deg   = (int*)take((size_t)NN * 4);
  int*            cursor= (int*)take((size_t)NN * 4);
  float*          degf  = (float*)take((size_t)NN * 4);
  float*          wcomp = (float*)take((size_t)3 * 256 * 128 * 4);
  float*          c2b   = (float*)take((size_t)3 * 128 * 4);
  unsigned short* wembf = (unsigned short*)take((size_t)16 * 64 * 8 * 2);
  unsigned short* w1af  = (unsigned short*)take((size_t)3 * 64 * 64 * 8 * 2);
  unsigned short* w1bf  = (unsigned short*)take((size_t)3 * 64 * 64 * 8 * 2);
  unsigned short* w1cf  = (unsigned short*)take((size_t)3 * 16 * 64 * 8 * 2);
  unsigned short* wupdf = (unsigned short*)take((size_t)3 * 96 * 64 * 8 * 2);
  unsigned short* wprojf= (unsigned short*)take((size_t)64 * 64 * 8 * 2);
  (void)ws_size; (void)n_in; (void)in_sizes;

  // ---- one-time prep ----
  hipMemsetAsync(deg, 0, (size_t)NN * 4, stream);
  hist_kernel<<<2048, 256, 0, stream>>>(eidx, deg);
  scan_kernel<<<1, 1024, 0, stream>>>(deg, cursor, degf);
  fill_dsts_kernel<<<128, 256, 0, stream>>>(deg, cursor, dsts);
  scatter_kernel<<<2048, 256, 0, stream>>>(eidx, ea, cursor, srcs, ea_s);
  wcomp_kernel<<<386, 256, 0, stream>>>(msg_w2, upd_w, msg_b2, wcomp, c2b);
  prep_all_kernel<<<200, 256, 0, stream>>>(emb_w, msg_w1, upd_w, wcomp, proj_w,
                                           wembf, w1af, w1bf, w1cf, wupdf, wprojf);

  node_emb_kernel<<<512, 256, 0, stream>>>(x, wembf, emb_b, h_bf);

  for (int l = 0; l < 3; ++l) {
    pq_kernel<<<512, 256, 0, stream>>>(h_bf, w1af + (size_t)l * 32768, w1bf + (size_t)l * 32768,
                                       msg_b1 + l * 256, Pb, Qb, haggr);
    edge_kernel11<<<NE / 32, 64, 0, stream>>>(Pb, Qb, dsts, srcs, ea_s,
                                              w1cf + (size_t)l * 8192, haggr);
    upd_kernel2<<<512, 256, 0, stream>>>(h_bf, haggr, degf,
                                         wupdf + (size_t)l * 49152, upd_b + l * 128,
                                         c2b + l * 128,
                                         uln_g + l * 128, uln_b + l * 128,
                                         nrm_g + l * 128, nrm_b + l * 128, h_bf);
  }

  proj_kernel<<<512, 256, 0, stream>>>(h_bf, wprojf, proj_b, (float*)d_out,
                                       (float*)d_out + (size_t)NN * 256);
}

// Round 16
// 445.160 us; speedup vs baseline: 1.0338x; 1.0338x over previous
//
#include <hip/hip_runtime.h>

#define NN 32768   // nodes
#define NE 524288  // edges

typedef __attribute__((ext_vector_type(8))) short bf16x8;
typedef __attribute__((ext_vector_type(4))) float f32x4;

__device__ __forceinline__ unsigned short f2bf(float f) {
  unsigned int u = __float_as_uint(f);
  unsigned int r = (u + 0x7FFFu + ((u >> 16) & 1u)) >> 16;
  return (unsigned short)r;
}
__device__ __forceinline__ float bf2f(unsigned short s) {
  return __uint_as_float(((unsigned int)s) << 16);
}

// wave-level LDS fence: HW-drain this wave's DS ops + stop compiler reordering
__device__ __forceinline__ void lds_fence_wave() {
  asm volatile("s_waitcnt lgkmcnt(0)" ::: "memory");
  __builtin_amdgcn_sched_barrier(0);
}

// ---------------- generic fragment pack (device body) ----------------
// B-operand fragment order: frag fi = kc*(N/16)+nt, elem j:
// v[j] = W[l][row0 + kc*32 + 8*(lane>>4) + j][nt*16 + (lane&15)]
__device__ __forceinline__ void prep_frag_body(
    const float* __restrict__ W, int row0, int ldw, long lstrW,
    unsigned short* __restrict__ out, int outOff, int outLstr,
    int K, int N, int t, int total) {
  if (t >= total) return;
  int lane = t & 63, fi = t >> 6;
  int FR = (K >> 5) * (N >> 4);
  int l = fi / FR; fi -= l * FR;
  int NT = N >> 4;
  int nt = fi % NT, kc = fi / NT;
  int i = lane & 15, g = lane >> 4;
  const float* base = W + (long)l * lstrW;
  bf16x8 v;
#pragma unroll
  for (int j = 0; j < 8; ++j)
    v[j] = (short)f2bf(base[(long)(row0 + kc * 32 + g * 8 + j) * ldw + nt * 16 + i]);
  reinterpret_cast<bf16x8*>(out)[(long)(l * outLstr + outOff + fi) * 64 + lane] = v;
}

// all weight fragment packs in one dispatch (block-range switch)
__global__ void prep_all_kernel(const float* __restrict__ emb_w,
                                const float* __restrict__ msg_w1,
                                const float* __restrict__ upd_w,
                                const float* __restrict__ wcomp,
                                const float* __restrict__ proj_w,
                                unsigned short* __restrict__ wembf,
                                unsigned short* __restrict__ w1af,
                                unsigned short* __restrict__ w1bf,
                                unsigned short* __restrict__ w1cf,
                                unsigned short* __restrict__ wupdf,
                                unsigned short* __restrict__ wprojf) {
  int b = blockIdx.x, tid = threadIdx.x;
  if (b < 4)        prep_frag_body(emb_w,  0,   128, 0,     wembf,  0,  16, 64,  128, b * 256 + tid, 1024);
  else if (b < 52)  prep_frag_body(msg_w1, 0,   256, 73728, w1af,   0,  64, 128, 256, (b - 4) * 256 + tid, 12288);
  else if (b < 100) prep_frag_body(msg_w1, 128, 256, 73728, w1bf,   0,  64, 128, 256, (b - 52) * 256 + tid, 12288);
  else if (b < 112) prep_frag_body(msg_w1, 256, 256, 73728, w1cf,   0,  16, 32,  256, (b - 100) * 256 + tid, 3072);
  else if (b < 136) prep_frag_body(upd_w,  0,   128, 32768, wupdf,  0,  96, 128, 128, (b - 112) * 256 + tid, 6144);
  else if (b < 184) prep_frag_body(wcomp,  0,   128, 32768, wupdf,  32, 96, 256, 128, (b - 136) * 256 + tid, 12288);
  else              prep_frag_body(proj_w, 0,   256, 0,     wprojf, 0,  64, 128, 256, (b - 184) * 256 + tid, 4096);
}

// ---------------- Wcomp = W2 @ Wu_bot  (+ c2 = b2 @ Wu_bot tail) ----------
__global__ void wcomp_kernel(const float* __restrict__ W2, const float* __restrict__ Wu,
                             const float* __restrict__ b2,
                             float* __restrict__ out, float* __restrict__ c2out) {
  int t = blockIdx.x * 256 + threadIdx.x;
  if (t < 3 * 256 * 128) {
    int c = t & 127, a = (t >> 7) & 255, l = t >> 15;
    const float* w2 = W2 + (long)l * 32768 + a * 128;
    const float* wu = Wu + (long)l * 32768 + 128 * 128 + c;
    float s = 0.f;
#pragma unroll 8
    for (int j = 0; j < 128; ++j) s += w2[j] * wu[j * 128];
    out[t] = s;
  } else {
    int t2 = t - 3 * 256 * 128;
    if (t2 < 3 * 128) {
      int c = t2 & 127, l = t2 >> 7;
      const float* bb = b2 + l * 128;
      const float* wu = Wu + (long)l * 32768 + 128 * 128 + c;
      float s = 0.f;
#pragma unroll 8
      for (int j = 0; j < 128; ++j) s += bb[j] * wu[j * 128];
      c2out[t2] = s;
    }
  }
}

// ---------------- sort edges by dst ----------------
__global__ void hist_kernel(const int* __restrict__ eidx, int* __restrict__ deg) {
  int t = blockIdx.x * 256 + threadIdx.x;
  if (t < NE) atomicAdd(&deg[eidx[NE + t]], 1);
}

__global__ void scan_kernel(const int* __restrict__ deg, int* __restrict__ cursor,
                            float* __restrict__ degf) {
  __shared__ int lds[1024];
  int t = threadIdx.x;
  int vals[32];
  int s = 0;
#pragma unroll
  for (int j = 0; j < 32; ++j) {
    int d = deg[t * 32 + j];
    vals[j] = d; s += d;
    degf[t * 32 + j] = (float)d;
  }
  lds[t] = s;
  __syncthreads();
  for (int off = 1; off < 1024; off <<= 1) {
    int tmp = 0;
    if (t >= off) tmp = lds[t - off];
    __syncthreads();
    lds[t] += tmp;
    __syncthreads();
  }
  int run = lds[t] - s;  // exclusive prefix
#pragma unroll
  for (int j = 0; j < 32; ++j) { cursor[t * 32 + j] = run; run += vals[j]; }
}

// dsts is determined by the histogram: dsts[start_n .. start_n+deg_n) = n.
// Generate it coalesced instead of scatter's 16x-amplified random 4B writes.
__global__ void fill_dsts_kernel(const int* __restrict__ deg, const int* __restrict__ cursor,
                                 int* __restrict__ dsts) {
  int n = blockIdx.x * 256 + threadIdx.x;
  if (n >= NN) return;
  int st = cursor[n], de = deg[n];
  for (int j = 0; j < de; ++j) dsts[st + j] = n;
}

// scatter edges into dst-sorted order (srcs + permuted/cvt edge_attr only)
__global__ void scatter_kernel(const int* __restrict__ eidx, const float* __restrict__ ea,
                               int* __restrict__ cursor,
                               int* __restrict__ srcs,
                               unsigned short* __restrict__ ea_s) {
  int t = blockIdx.x * 256 + threadIdx.x;
  if (t >= NE) return;
  int d = eidx[NE + t], s = eidx[t];
  int pos = atomicAdd(&cursor[d], 1);
  srcs[pos] = s;
  const float4* ep = reinterpret_cast<const float4*>(ea + (long)t * 32);
  unsigned short* op = ea_s + (long)pos * 32;
#pragma unroll
  for (int q = 0; q < 4; ++q) {
    float4 f0 = ep[2 * q], f1 = ep[2 * q + 1];
    bf16x8 v;
    v[0] = (short)f2bf(f0.x); v[1] = (short)f2bf(f0.y);
    v[2] = (short)f2bf(f0.z); v[3] = (short)f2bf(f0.w);
    v[4] = (short)f2bf(f1.x); v[5] = (short)f2bf(f1.y);
    v[6] = (short)f2bf(f1.z); v[7] = (short)f2bf(f1.w);
    *reinterpret_cast<bf16x8*>(op + q * 8) = v;
  }
}

// ---------------- node embedding: h = x @ We + be (bf16 spine only) --------
__global__ __launch_bounds__(256, 2)
void node_emb_kernel(const float* __restrict__ x,
                     const unsigned short* __restrict__ wf,
                     const float* __restrict__ bias,
                     unsigned short* __restrict__ h_bf) {
  int tid = threadIdx.x, lane = tid & 63, w = tid >> 6;
  int i = lane & 15, g = lane >> 4;
  int nbase = blockIdx.x * 64 + w * 16;
  f32x4 zero = {0.f, 0.f, 0.f, 0.f};
  f32x4 acc[8];
#pragma unroll
  for (int nt = 0; nt < 8; ++nt) acc[nt] = zero;
#pragma unroll
  for (int kc = 0; kc < 2; ++kc) {
    const float* xp = x + (nbase + i) * 64 + kc * 32 + g * 8;
    float4 f0 = *reinterpret_cast<const float4*>(xp);
    float4 f1 = *reinterpret_cast<const float4*>(xp + 4);
    bf16x8 af;
    af[0] = (short)f2bf(f0.x); af[1] = (short)f2bf(f0.y);
    af[2] = (short)f2bf(f0.z); af[3] = (short)f2bf(f0.w);
    af[4] = (short)f2bf(f1.x); af[5] = (short)f2bf(f1.y);
    af[6] = (short)f2bf(f1.z); af[7] = (short)f2bf(f1.w);
#pragma unroll
    for (int nt = 0; nt < 8; ++nt) {
      bf16x8 bf = reinterpret_cast<const bf16x8*>(wf)[(kc * 8 + nt) * 64 + lane];
      acc[nt] = __builtin_amdgcn_mfma_f32_16x16x32_bf16(af, bf, acc[nt], 0, 0, 0);
    }
  }
#pragma unroll
  for (int nt = 0; nt < 8; ++nt) {
    int c = nt * 16 + i;
    float b = bias[c];
#pragma unroll
    for (int r = 0; r < 4; ++r) {
      int node = nbase + 4 * g + r;
      h_bf[node * 128 + c] = f2bf(acc[nt][r] + b);
    }
  }
}

// ---------------- P = h@W1a + b1, Q = h@W1b; zero haggr; coalesced stores --
__global__ __launch_bounds__(256, 2)
void pq_kernel(const unsigned short* __restrict__ h_bf,
               const unsigned short* __restrict__ wfa,
               const unsigned short* __restrict__ wfb,
               const float* __restrict__ b1,
               unsigned short* __restrict__ P, unsigned short* __restrict__ Q,
               float* __restrict__ haggr) {
  __shared__ unsigned short xpose[64 * 264];  // 33792 B repack buffer
  int tid = threadIdx.x, lane = tid & 63, w = tid >> 6;
  int i = lane & 15, g = lane >> 4;
  int nbase = blockIdx.x * 64 + w * 16;
  // zero this block's 64 haggr rows (replaces hipMemsetAsync)
  {
    const float4 zz = make_float4(0.f, 0.f, 0.f, 0.f);
    float4* hz = reinterpret_cast<float4*>(haggr + (long)blockIdx.x * 64 * 256);
#pragma unroll
    for (int it = 0; it < 16; ++it) hz[tid + 256 * it] = zz;
  }
  f32x4 zero = {0.f, 0.f, 0.f, 0.f};
  f32x4 accP[16], accQ[16];
#pragma unroll
  for (int nt = 0; nt < 16; ++nt) { accP[nt] = zero; accQ[nt] = zero; }
#pragma unroll
  for (int kc = 0; kc < 4; ++kc) {
    bf16x8 af = *reinterpret_cast<const bf16x8*>(h_bf + (nbase + i) * 128 + kc * 32 + g * 8);
#pragma unroll
    for (int nt = 0; nt < 16; ++nt) {
      bf16x8 ba = reinterpret_cast<const bf16x8*>(wfa)[(kc * 16 + nt) * 64 + lane];
      accP[nt] = __builtin_amdgcn_mfma_f32_16x16x32_bf16(af, ba, accP[nt], 0, 0, 0);
      bf16x8 bb = reinterpret_cast<const bf16x8*>(wfb)[(kc * 16 + nt) * 64 + lane];
      accQ[nt] = __builtin_amdgcn_mfma_f32_16x16x32_bf16(af, bb, accQ[nt], 0, 0, 0);
    }
  }
  const int rowBase = blockIdx.x * 64;
  // P: transpose through LDS -> coalesced bf16x8 stores
#pragma unroll
  for (int nt = 0; nt < 16; ++nt) {
    int c = nt * 16 + i;
    float b = b1[c];
#pragma unroll
    for (int r = 0; r < 4; ++r)
      xpose[(w * 16 + 4 * g + r) * 264 + c] = f2bf(accP[nt][r] + b);
  }
  __syncthreads();
#pragma unroll
  for (int it = 0; it < 8; ++it) {
    int idx = tid + 256 * it;
    int row = idx >> 5, ch8 = (idx & 31) * 8;
    bf16x8 v = *reinterpret_cast<const bf16x8*>(&xpose[row * 264 + ch8]);
    *reinterpret_cast<bf16x8*>(&P[(long)(rowBase + row) * 256 + ch8]) = v;
  }
  __syncthreads();
  // Q: same, reusing the buffer
#pragma unroll
  for (int nt = 0; nt < 16; ++nt) {
    int c = nt * 16 + i;
#pragma unroll
    for (int r = 0; r < 4; ++r)
      xpose[(w * 16 + 4 * g + r) * 264 + c] = f2bf(accQ[nt][r]);
  }
  __syncthreads();
#pragma unroll
  for (int it = 0; it < 8; ++it) {
    int idx = tid + 256 * it;
    int row = idx >> 5, ch8 = (idx & 31) * 8;
    bf16x8 v = *reinterpret_cast<const bf16x8*>(&xpose[row * 264 + ch8]);
    *reinterpret_cast<bf16x8*>(&Q[(long)(rowBase + row) * 256 + ch8]) = v;
  }
}

// ---------------- edge kernel v10: readlane indices + early Q/P issue ------
// hidden = relu(P[dst] + Q[src] + R), dst-segmented sum -> haggr (fp32).
// (R14-proven shape: 128 threads, 16 edges/wave, 2 waves/block.)
#define RP 264
__global__ __launch_bounds__(128, 4)
void edge_kernel10(const unsigned short* __restrict__ P,
                   const unsigned short* __restrict__ Q,
                   const int* __restrict__ dsts, const int* __restrict__ srcs,
                   const unsigned short* __restrict__ ea_s,
                   const unsigned short* __restrict__ w1cf,
                   float* __restrict__ haggr) {
  __shared__ unsigned short R[32 * RP];   // 16896 B
  __shared__ float xch[2][256];           // per-wave flush transpose
  const int tid = threadIdx.x;
  const int lane = tid & 63, w = tid >> 6;
  const int i = lane & 15, g = lane >> 4;
  // XCD-chunked bijective swizzle: nwg = 16384 = 8 * 2048
  const int bid = blockIdx.x;
  const int swz = (bid & 7) * 2048 + (bid >> 3);
  const int p0 = swz * 32;
  const int kb = w * 16;

  // dst/src for this wave's 16 edges: one vector load each, then readlane
  int d16 = dsts[p0 + kb + (lane & 15)];
  int s16 = srcs[p0 + kb + (lane & 15)];
  int dvs[16], svs[16];
#pragma unroll
  for (int k = 0; k < 16; ++k) {
    dvs[k] = __builtin_amdgcn_readlane(d16, k);
    svs[k] = __builtin_amdgcn_readlane(s16, k);
  }

  const int c4 = lane * 4;
  // issue the 16 Q-row gathers + first P row early (hide under R MFMA)
  ushort4 qv[16];
#pragma unroll
  for (int k = 0; k < 16; ++k)
    qv[k] = *reinterpret_cast<const ushort4*>(Q + (long)svs[k] * 256 + c4);
  ushort4 pv0 = *reinterpret_cast<const ushort4*>(P + (long)dvs[0] * 256 + c4);

  // R^T = W1c^T @ ea^T for this wave's 16 edges: lane holds channels
  // m*16+4g..+3 of edge (kb+i) -> b64 stores into R rows
  {
    bf16x8 bfrag = *reinterpret_cast<const bf16x8*>(ea_s + (long)(p0 + kb + i) * 32 + g * 8);
    f32x4 zero = {0.f, 0.f, 0.f, 0.f};
    f32x4 acc[16];
#pragma unroll
    for (int m = 0; m < 16; ++m) acc[m] = zero;
#pragma unroll
    for (int m = 0; m < 16; ++m) {
      bf16x8 afrag = reinterpret_cast<const bf16x8*>(w1cf)[m * 64 + lane];
      acc[m] = __builtin_amdgcn_mfma_f32_16x16x32_bf16(afrag, bfrag, acc[m], 0, 0, 0);
    }
#pragma unroll
    for (int m = 0; m < 16; ++m) {
      union { unsigned short s[4]; unsigned long long u; } pk;
#pragma unroll
      for (int r = 0; r < 4; ++r) pk.s[r] = f2bf(acc[m][r]);
      *reinterpret_cast<unsigned long long*>(&R[(kb + i) * RP + m * 16 + 4 * g]) = pk.u;
    }
  }

  float pf[4];
  pf[0] = bf2f(pv0.x); pf[1] = bf2f(pv0.y); pf[2] = bf2f(pv0.z); pf[3] = bf2f(pv0.w);
  int dvPrev = dvs[0];

  lds_fence_wave();  // R wave-local producer->consumer ordering

  float acc4[4] = {0.f, 0.f, 0.f, 0.f};
#pragma unroll
  for (int k = 0; k < 16; ++k) {
    int dv = dvs[k];
    if (dv != dvPrev) {  // scalar branch (dvs in SGPRs)
      *reinterpret_cast<float4*>(&xch[w][c4]) = make_float4(acc4[0], acc4[1], acc4[2], acc4[3]);
      lds_fence_wave();
      float* hp = haggr + (long)dvPrev * 256;
#pragma unroll
      for (int j = 0; j < 4; ++j) atomicAdd(hp + lane + 64 * j, xch[w][lane + 64 * j]);
      acc4[0] = acc4[1] = acc4[2] = acc4[3] = 0.f;
      ushort4 pv = *reinterpret_cast<const ushort4*>(P + (long)dv * 256 + c4);
      pf[0] = bf2f(pv.x); pf[1] = bf2f(pv.y); pf[2] = bf2f(pv.z); pf[3] = bf2f(pv.w);
      dvPrev = dv;
    }
    ushort4 rv = *reinterpret_cast<const ushort4*>(&R[(kb + k) * RP + c4]);
    float v0 = pf[0] + bf2f(qv[k].x) + bf2f(rv.x);
    float v1 = pf[1] + bf2f(qv[k].y) + bf2f(rv.y);
    float v2 = pf[2] + bf2f(qv[k].z) + bf2f(rv.z);
    float v3 = pf[3] + bf2f(qv[k].w) + bf2f(rv.w);
    acc4[0] += v0 > 0.f ? v0 : 0.f;
    acc4[1] += v1 > 0.f ? v1 : 0.f;
    acc4[2] += v2 > 0.f ? v2 : 0.f;
    acc4[3] += v3 > 0.f ? v3 : 0.f;
  }
  {
    *reinterpret_cast<float4*>(&xch[w][c4]) = make_float4(acc4[0], acc4[1], acc4[2], acc4[3]);
    lds_fence_wave();
    float* hp = haggr + (long)dvPrev * 256;
#pragma unroll
    for (int j = 0; j < 4; ++j) atomicAdd(hp + lane + 64 * j, xch[w][lane + 64 * j]);
  }
}

// ---------------- update: u=[h|haggr]@W+ub+deg*c2, relu,LN,+h,LN ----------
// residual taken from h_bf (bf16 spine; no fp32 h shadow)
__global__ __launch_bounds__(256, 2)
void upd_kernel2(const unsigned short* __restrict__ h_bf_in,
                 const float* __restrict__ haggr,
                 const float* __restrict__ degf,
                 const unsigned short* __restrict__ wf,
                 const float* __restrict__ ub, const float* __restrict__ c2,
                 const float* __restrict__ g1, const float* __restrict__ be1,
                 const float* __restrict__ g2, const float* __restrict__ be2,
                 unsigned short* __restrict__ h_bf_out) {
  int tid = threadIdx.x, lane = tid & 63, w = tid >> 6;
  int i = lane & 15, g = lane >> 4;
  int nbase = blockIdx.x * 64 + w * 16;
  f32x4 zero = {0.f, 0.f, 0.f, 0.f};
  f32x4 acc[8];
#pragma unroll
  for (int nt = 0; nt < 8; ++nt) acc[nt] = zero;
#pragma unroll
  for (int kc = 0; kc < 12; ++kc) {
    bf16x8 af;
    if (kc < 4) {
      af = *reinterpret_cast<const bf16x8*>(h_bf_in + (nbase + i) * 128 + kc * 32 + g * 8);
    } else {
      const float* ap = haggr + (long)(nbase + i) * 256 + (kc - 4) * 32 + g * 8;
      float4 f0 = *reinterpret_cast<const float4*>(ap);
      float4 f1 = *reinterpret_cast<const float4*>(ap + 4);
      af[0] = (short)f2bf(f0.x); af[1] = (short)f2bf(f0.y);
      af[2] = (short)f2bf(f0.z); af[3] = (short)f2bf(f0.w);
      af[4] = (short)f2bf(f1.x); af[5] = (short)f2bf(f1.y);
      af[6] = (short)f2bf(f1.z); af[7] = (short)f2bf(f1.w);
    }
#pragma unroll
    for (int nt = 0; nt < 8; ++nt) {
      bf16x8 bf = reinterpret_cast<const bf16x8*>(wf)[(kc * 8 + nt) * 64 + lane];
      acc[nt] = __builtin_amdgcn_mfma_f32_16x16x32_bf16(af, bf, acc[nt], 0, 0, 0);
    }
  }
  float vv[8][4];
#pragma unroll
  for (int nt = 0; nt < 8; ++nt) {
    int c = nt * 16 + i;
    float b = ub[c], cc = c2[c];
#pragma unroll
    for (int r = 0; r < 4; ++r) {
      int node = nbase + 4 * g + r;
      float t = acc[nt][r] + b + degf[node] * cc;
      vv[nt][r] = t > 0.f ? t : 0.f;
    }
  }
#pragma unroll
  for (int r = 0; r < 4; ++r) {
    float s = 0.f, s2 = 0.f;
#pragma unroll
    for (int nt = 0; nt < 8; ++nt) { s += vv[nt][r]; s2 += vv[nt][r] * vv[nt][r]; }
#pragma unroll
    for (int mk = 1; mk < 16; mk <<= 1) { s += __shfl_xor(s, mk, 64); s2 += __shfl_xor(s2, mk, 64); }
    float mean = s * (1.f / 128.f);
    float var = s2 * (1.f / 128.f) - mean * mean;
    float inv = rsqrtf(var + 1e-5f);
    int node = nbase + 4 * g + r;
    float tv[8];
    float sb = 0.f, sb2 = 0.f;
#pragma unroll
    for (int nt = 0; nt < 8; ++nt) {
      int c = nt * 16 + i;
      float u = (vv[nt][r] - mean) * inv * g1[c] + be1[c];
      float t = bf2f(h_bf_in[node * 128 + c]) + u;  // bf16 residual spine
      tv[nt] = t;
      sb += t; sb2 += t * t;
    }
#pragma unroll
    for (int mk = 1; mk < 16; mk <<= 1) { sb += __shfl_xor(sb, mk, 64); sb2 += __shfl_xor(sb2, mk, 64); }
    float mean2 = sb * (1.f / 128.f);
    float var2 = sb2 * (1.f / 128.f) - mean2 * mean2;
    float inv2 = rsqrtf(var2 + 1e-5f);
#pragma unroll
    for (int nt = 0; nt < 8; ++nt) {
      int c = nt * 16 + i;
      float o = (tv[nt] - mean2) * inv2 * g2[c] + be2[c];
      h_bf_out[node * 128 + c] = f2bf(o);
    }
  }
}

// ---------------- projection (+ mask fill) ----------------
__global__ __launch_bounds__(256, 2)
void proj_kernel(const unsigned short* __restrict__ h_bf,
                 const unsigned short* __restrict__ wf,
                 const float* __restrict__ bias,
                 float* __restrict__ out, float* __restrict__ mask) {
  int tid = threadIdx.x, lane = tid & 63, w = tid >> 6;
  int i = lane & 15, g = lane >> 4;
  int nbase = blockIdx.x * 64 + w * 16;
  if (tid < 64) mask[blockIdx.x * 64 + tid] = 1.0f;
  f32x4 zero = {0.f, 0.f, 0.f, 0.f};
  f32x4 acc[16];
#pragma unroll
  for (int nt = 0; nt < 16; ++nt) acc[nt] = zero;
#pragma unroll
  for (int kc = 0; kc < 4; ++kc) {
    bf16x8 af = *reinterpret_cast<const bf16x8*>(h_bf + (nbase + i) * 128 + kc * 32 + g * 8);
#pragma unroll
    for (int nt = 0; nt < 16; ++nt) {
      bf16x8 bf = reinterpret_cast<const bf16x8*>(wf)[(kc * 16 + nt) * 64 + lane];
      acc[nt] = __builtin_amdgcn_mfma_f32_16x16x32_bf16(af, bf, acc[nt], 0, 0, 0);
    }
  }
#pragma unroll
  for (int nt = 0; nt < 16; ++nt) {
    int c = nt * 16 + i;
    float b = bias[c];
#pragma unroll
    for (int r = 0; r < 4; ++r) {
      int node = nbase + 4 * g + r;
      out[(long)node * 256 + c] = acc[nt][r] + b;
    }
  }
}

// ---------------- launch ----------------
extern "C" void kernel_launch(void* const* d_in, const int* in_sizes, int n_in,
                              void* d_out, int out_size, void* d_ws, size_t ws_size,
                              hipStream_t stream) {
  const float* x      = (const float*)d_in[0];
  const float* ea     = (const float*)d_in[1];
  const float* emb_w  = (const float*)d_in[2];
  const float* emb_b  = (const float*)d_in[3];
  const float* msg_w1 = (const float*)d_in[4];
  const float* msg_b1 = (const float*)d_in[5];
  const float* msg_w2 = (const float*)d_in[6];
  const float* msg_b2 = (const float*)d_in[7];
  const float* upd_w  = (const float*)d_in[8];
  const float* upd_b  = (const float*)d_in[9];
  const float* uln_g  = (const float*)d_in[10];
  const float* uln_b  = (const float*)d_in[11];
  const float* nrm_g  = (const float*)d_in[12];
  const float* nrm_b  = (const float*)d_in[13];
  const float* proj_w = (const float*)d_in[14];
  const float* proj_b = (const float*)d_in[15];
  const int*   eidx   = (const int*)d_in[16];

  char* ws = (char*)d_ws;
  size_t off = 0;
  auto take = [&](size_t b) { char* p = ws + off; off = (off + b + 255) & ~(size_t)255; return p; };
  unsigned short* h_bf  = (unsigned short*)take((size_t)NN * 128 * 2);
  unsigned short* Pb    = (unsigned short*)take((size_t)NN * 256 * 2);
  unsigned short* Qb    = (unsigned short*)take((size_t)NN * 256 * 2);
  float*          haggr = (float*)take((size_t)NN * 256 * 4);
  unsigned short* ea_s  = (unsigned short*)take((size_t)NE * 32 * 2);
  int*            dsts  = (int*)take((size_t)NE * 4);
  int*            srcs  = (int*)take((size_t)NE * 4);
  int*            deg   = (int*)take((size_t)NN * 4);
  int*            cursor= (int*)take((size_t)NN * 4);
  float*          degf  = (float*)take((size_t)NN * 4);
  float*          wcomp = (float*)take((size_t)3 * 256 * 128 * 4);
  float*          c2b   = (float*)take((size_t)3 * 128 * 4);
  unsigned short* wembf = (unsigned short*)take((size_t)16 * 64 * 8 * 2);
  unsigned short* w1af  = (unsigned short*)take((size_t)3 * 64 * 64 * 8 * 2);
  unsigned short* w1bf  = (unsigned short*)take((size_t)3 * 64 * 64 * 8 * 2);
  unsigned short* w1cf  = (unsigned short*)take((size_t)3 * 16 * 64 * 8 * 2);
  unsigned short* wupdf = (unsigned short*)take((size_t)3 * 96 * 64 * 8 * 2);
  unsigned short* wprojf= (unsigned short*)take((size_t)64 * 64 * 8 * 2);
  (void)ws_size; (void)n_in; (void)in_sizes;

  // ---- one-time prep ----
  hipMemsetAsync(deg, 0, (size_t)NN * 4, stream);
  hist_kernel<<<2048, 256, 0, stream>>>(eidx, deg);
  scan_kernel<<<1, 1024, 0, stream>>>(deg, cursor, degf);
  fill_dsts_kernel<<<128, 256, 0, stream>>>(deg, cursor, dsts);
  scatter_kernel<<<2048, 256, 0, stream>>>(eidx, ea, cursor, srcs, ea_s);
  wcomp_kernel<<<386, 256, 0, stream>>>(msg_w2, upd_w, msg_b2, wcomp, c2b);
  prep_all_kernel<<<200, 256, 0, stream>>>(emb_w, msg_w1, upd_w, wcomp, proj_w,
                                           wembf, w1af, w1bf, w1cf, wupdf, wprojf);

  node_emb_kernel<<<512, 256, 0, stream>>>(x, wembf, emb_b, h_bf);

  for (int l = 0; l < 3; ++l) {
    pq_kernel<<<512, 256, 0, stream>>>(h_bf, w1af + (size_t)l * 32768, w1bf + (size_t)l * 32768,
                                       msg_b1 + l * 256, Pb, Qb, haggr);
    edge_kernel10<<<NE / 32, 128, 0, stream>>>(Pb, Qb, dsts, srcs, ea_s,
                                               w1cf + (size_t)l * 8192, haggr);
    upd_kernel2<<<512, 256, 0, stream>>>(h_bf, haggr, degf,
                                         wupdf + (size_t)l * 49152, upd_b + l * 128,
                                         c2b + l * 128,
                                         uln_g + l * 128, uln_b + l * 128,
                                         nrm_g + l * 128, nrm_b + l * 128, h_bf);
  }

  proj_kernel<<<512, 256, 0, stream>>>(h_bf, wprojf, proj_b, (float*)d_out,
                                       (float*)d_out + (size_t)NN * 256);
}